// Round 1
// baseline (676.394 us; speedup 1.0000x reference)
//
#include <hip/hip_runtime.h>
#include <math.h>

// Problem: N=8192 nodes, D=256 features, H=64 hidden.
// out = [h_out (N*D floats), e (N floats)] concatenated, fp32.

// ---------------- Kernel 1: per-node gate e = sigmoid(relu(h@W1+b1)@W2+b2) ----
// grid: N blocks x H(=64) threads. Lane k owns hidden unit k.
__global__ void gate_kernel(const float* __restrict__ h,
                            const float* __restrict__ W1,
                            const float* __restrict__ b1,
                            const float* __restrict__ W2,
                            const float* __restrict__ b2,
                            float* __restrict__ e_out,
                            int D, int H) {
    const int i = blockIdx.x;
    const int k = threadIdx.x;                 // hidden unit index, 0..63
    const float* hrow = h + (size_t)i * D;
    float acc = 0.f;
    // W1[d*H + k]: lane k reads consecutive addresses -> coalesced; W1 is 64 KB, L2-resident.
    // hrow[d] is wave-uniform -> scalar load.
    for (int d = 0; d < D; ++d)
        acc = fmaf(hrow[d], W1[(size_t)d * H + k], acc);
    acc += b1[k];
    acc = fmaxf(acc, 0.f);
    float v = acc * W2[k];
    // wave(64)-reduce
    #pragma unroll
    for (int off = 32; off > 0; off >>= 1)
        v += __shfl_down(v, off);
    if (k == 0) {
        float z = v + b2[0];
        e_out[i] = 1.f / (1.f + expf(-z));
    }
}

// ---------------- Kernel 2: h_out[i,:] = sum_{j: A[i,j]>0} e[j] * h[j,:] -------
// grid: N blocks x D(=256) threads. Lane d owns feature d of the output row.
// Scans A-row in chunks of 1024 elements (256 threads x float4, coalesced),
// compacts nonzero (j, e[j]) into LDS, then accumulates.
__global__ void agg_kernel(const float* __restrict__ A,
                           const float* __restrict__ h,
                           const float* __restrict__ e,
                           float* __restrict__ h_out,
                           int N, int D) {
    constexpr int CHUNK = 1024;                // 256 threads * 4 floats
    __shared__ int   s_idx[CHUNK];
    __shared__ float s_val[CHUNK];
    __shared__ int   s_cnt;

    const int i   = blockIdx.x;
    const int tid = threadIdx.x;
    const float4* Arow = reinterpret_cast<const float4*>(A + (size_t)i * N);

    float acc = 0.f;
    for (int base = 0; base < N; base += CHUNK) {
        if (tid == 0) s_cnt = 0;
        __syncthreads();

        // coalesced 16B/lane scan of this chunk
        float4 a4 = Arow[(base >> 2) + tid];
        int j0 = base + tid * 4;
        if (a4.x > 0.f) { int p = atomicAdd(&s_cnt, 1); s_idx[p] = j0;     s_val[p] = e[j0]; }
        if (a4.y > 0.f) { int p = atomicAdd(&s_cnt, 1); s_idx[p] = j0 + 1; s_val[p] = e[j0 + 1]; }
        if (a4.z > 0.f) { int p = atomicAdd(&s_cnt, 1); s_idx[p] = j0 + 2; s_val[p] = e[j0 + 2]; }
        if (a4.w > 0.f) { int p = atomicAdd(&s_cnt, 1); s_idx[p] = j0 + 3; s_val[p] = e[j0 + 3]; }
        __syncthreads();

        const int c = s_cnt;
        for (int p = 0; p < c; ++p) {
            // s_idx/s_val broadcast from LDS; h read coalesced (lane d -> h[j*D+d])
            acc = fmaf(s_val[p], h[(size_t)s_idx[p] * D + tid], acc);
        }
        __syncthreads();
    }
    h_out[(size_t)i * D + tid] = acc;
}

extern "C" void kernel_launch(void* const* d_in, const int* in_sizes, int n_in,
                              void* d_out, int out_size, void* d_ws, size_t ws_size,
                              hipStream_t stream) {
    const float* A  = (const float*)d_in[0];   // [N, N]
    const float* h  = (const float*)d_in[1];   // [N, D]
    const float* W1 = (const float*)d_in[2];   // [D, H]
    const float* b1 = (const float*)d_in[3];   // [H]
    const float* W2 = (const float*)d_in[4];   // [H, 1]
    const float* b2 = (const float*)d_in[5];   // [1]

    const int H = in_sizes[3];                 // 64
    const int D = in_sizes[2] / H;             // 256
    const int N = in_sizes[1] / D;             // 8192

    float* out   = (float*)d_out;
    float* h_out = out;                        // N*D
    float* e_out = out + (size_t)N * D;        // N

    gate_kernel<<<N, H, 0, stream>>>(h, W1, b1, W2, b2, e_out, D, H);
    agg_kernel<<<N, D, 0, stream>>>(A, h, e_out, h_out, N, D);
}

// Round 2
// 420.023 us; speedup vs baseline: 1.6104x; 1.6104x over previous
//
#include <hip/hip_runtime.h>
#include <math.h>

// Problem: N=8192 nodes, D=256 features, H=64 hidden.
// out = [h_out (N*D floats), e (N floats)] concatenated, fp32.

// ---------------- Kernel 1: per-node gate e = sigmoid(relu(h@W1+b1)@W2+b2) ----
// Block = 256 threads (4 waves), stages all of W1 (64 KB) in LDS once.
// Each wave handles 4 of the block's 16 rows; lane k owns hidden unit k.
// LDS reads W1s[d*64+k]: lanes consecutive -> 2 lanes/bank (conflict-free).
__global__ __launch_bounds__(256) void gate_kernel(const float* __restrict__ h,
                                                   const float* __restrict__ W1,
                                                   const float* __restrict__ b1,
                                                   const float* __restrict__ W2,
                                                   const float* __restrict__ b2,
                                                   float* __restrict__ e_out,
                                                   int N) {
    __shared__ float W1s[256 * 64];            // 64 KB
    const int tid = threadIdx.x;

    // cooperative W1 load: 4096 float4 / 256 threads = 16 each, coalesced
    const float4* W1v = reinterpret_cast<const float4*>(W1);
    float4* W1sv = reinterpret_cast<float4*>(W1s);
    #pragma unroll
    for (int t = 0; t < 16; ++t) W1sv[tid + 256 * t] = W1v[tid + 256 * t];
    __syncthreads();

    const int wave = tid >> 6;
    const int k    = tid & 63;                 // hidden unit
    const float b1k = b1[k];
    const float w2k = W2[k];
    const float b2v = b2[0];

    const int base = blockIdx.x * 16;
    for (int r = wave; r < 16; r += 4) {
        const int i = base + r;
        if (i >= N) break;
        const float4* hv = reinterpret_cast<const float4*>(h + (size_t)i * 256);
        float acc = 0.f;
        #pragma unroll 4
        for (int d4 = 0; d4 < 64; ++d4) {
            float4 a = hv[d4];                 // wave-uniform broadcast load
            const int d = d4 * 4;
            acc = fmaf(a.x, W1s[(d + 0) * 64 + k], acc);
            acc = fmaf(a.y, W1s[(d + 1) * 64 + k], acc);
            acc = fmaf(a.z, W1s[(d + 2) * 64 + k], acc);
            acc = fmaf(a.w, W1s[(d + 3) * 64 + k], acc);
        }
        float v = fmaxf(acc + b1k, 0.f) * w2k;
        #pragma unroll
        for (int off = 32; off > 0; off >>= 1) v += __shfl_down(v, off);
        if (k == 0) e_out[i] = 1.f / (1.f + expf(-(v + b2v)));
    }
}

// ---------------- Kernel 2: h_out[i,:] = sum_{j: A[i,j]>0} e[j] * h[j,:] -------
// One wave per row. Lane d owns features 4d..4d+3 (float4 accumulator).
// Scan A-row as 32 float4 loads (1 KB/wave, coalesced), __ballot-compact the
// nonzero mask; set-bit iteration gives wave-uniform j -> e[j] is a scalar
// broadcast load, h[j] row is one coalesced 1 KB float4 load. No LDS, no syncs.
__global__ __launch_bounds__(256) void agg_kernel(const float* __restrict__ A,
                                                  const float* __restrict__ h,
                                                  const float* __restrict__ e,
                                                  float* __restrict__ h_out,
                                                  int N) {
    const int tid  = threadIdx.x;
    const int lane = tid & 63;
    const int i    = blockIdx.x * 4 + (tid >> 6);   // row per wave
    if (i >= N) return;

    const float4* Arow = reinterpret_cast<const float4*>(A + (size_t)i * N);
    const float4* hv   = reinterpret_cast<const float4*>(h);  // h[j][4d..] = hv[j*64+d]

    float4 acc = {0.f, 0.f, 0.f, 0.f};
    const int groups = N / 256;                     // 32
    for (int g = 0; g < groups; ++g) {
        float4 a4 = Arow[g * 64 + lane];            // columns g*256 + 4*lane + {0..3}
        unsigned long long mx = __ballot(a4.x > 0.f);
        unsigned long long my = __ballot(a4.y > 0.f);
        unsigned long long mz = __ballot(a4.z > 0.f);
        unsigned long long mw = __ballot(a4.w > 0.f);
        const int jb = g * 256;

        while (mx) { int b = __builtin_ctzll(mx); mx &= mx - 1;
            int j = jb + 4 * b + 0; float ej = e[j]; float4 hj = hv[(size_t)j * 64 + lane];
            acc.x = fmaf(ej, hj.x, acc.x); acc.y = fmaf(ej, hj.y, acc.y);
            acc.z = fmaf(ej, hj.z, acc.z); acc.w = fmaf(ej, hj.w, acc.w); }
        while (my) { int b = __builtin_ctzll(my); my &= my - 1;
            int j = jb + 4 * b + 1; float ej = e[j]; float4 hj = hv[(size_t)j * 64 + lane];
            acc.x = fmaf(ej, hj.x, acc.x); acc.y = fmaf(ej, hj.y, acc.y);
            acc.z = fmaf(ej, hj.z, acc.z); acc.w = fmaf(ej, hj.w, acc.w); }
        while (mz) { int b = __builtin_ctzll(mz); mz &= mz - 1;
            int j = jb + 4 * b + 2; float ej = e[j]; float4 hj = hv[(size_t)j * 64 + lane];
            acc.x = fmaf(ej, hj.x, acc.x); acc.y = fmaf(ej, hj.y, acc.y);
            acc.z = fmaf(ej, hj.z, acc.z); acc.w = fmaf(ej, hj.w, acc.w); }
        while (mw) { int b = __builtin_ctzll(mw); mw &= mw - 1;
            int j = jb + 4 * b + 3; float ej = e[j]; float4 hj = hv[(size_t)j * 64 + lane];
            acc.x = fmaf(ej, hj.x, acc.x); acc.y = fmaf(ej, hj.y, acc.y);
            acc.z = fmaf(ej, hj.z, acc.z); acc.w = fmaf(ej, hj.w, acc.w); }
    }

    float4* outv = reinterpret_cast<float4*>(h_out + (size_t)i * 256);
    outv[lane] = acc;
}

extern "C" void kernel_launch(void* const* d_in, const int* in_sizes, int n_in,
                              void* d_out, int out_size, void* d_ws, size_t ws_size,
                              hipStream_t stream) {
    const float* A  = (const float*)d_in[0];   // [N, N]
    const float* h  = (const float*)d_in[1];   // [N, D]
    const float* W1 = (const float*)d_in[2];   // [D, H]
    const float* b1 = (const float*)d_in[3];   // [H]
    const float* W2 = (const float*)d_in[4];   // [H, 1]
    const float* b2 = (const float*)d_in[5];   // [1]

    const int H = in_sizes[3];                 // 64
    const int D = in_sizes[2] / H;             // 256
    const int N = in_sizes[1] / D;             // 8192

    float* out   = (float*)d_out;
    float* h_out = out;                        // N*D
    float* e_out = out + (size_t)N * D;        // N

    gate_kernel<<<(N + 15) / 16, 256, 0, stream>>>(h, W1, b1, W2, b2, e_out, N);
    agg_kernel<<<(N + 3) / 4, 256, 0, stream>>>(A, h, e_out, h_out, N);
}

// Round 4
// 407.320 us; speedup vs baseline: 1.6606x; 1.0312x over previous
//
#include <hip/hip_runtime.h>
#include <math.h>

// Problem: N=8192 nodes, D=256 features, H=64 hidden.
// out = [h_out (N*D floats), e (N floats)] concatenated, fp32.

typedef float nfloat4 __attribute__((ext_vector_type(4)));  // native vec for __builtin_nontemporal_load

// ---------------- Kernel 1: per-node gate e = sigmoid(relu(h@W1+b1)@W2+b2) ----
// Block = 256 threads (4 waves), stages all of W1 (64 KB) in LDS once.
// Each wave handles 4 of the block's 16 rows; lane k owns hidden unit k.
__global__ __launch_bounds__(256) void gate_kernel(const float* __restrict__ h,
                                                   const float* __restrict__ W1,
                                                   const float* __restrict__ b1,
                                                   const float* __restrict__ W2,
                                                   const float* __restrict__ b2,
                                                   float* __restrict__ e_out,
                                                   int N) {
    __shared__ float W1s[256 * 64];            // 64 KB
    const int tid = threadIdx.x;

    const float4* W1v = reinterpret_cast<const float4*>(W1);
    float4* W1sv = reinterpret_cast<float4*>(W1s);
    #pragma unroll
    for (int t = 0; t < 16; ++t) W1sv[tid + 256 * t] = W1v[tid + 256 * t];
    __syncthreads();

    const int wave = tid >> 6;
    const int k    = tid & 63;                 // hidden unit
    const float b1k = b1[k];
    const float w2k = W2[k];
    const float b2v = b2[0];

    const int base = blockIdx.x * 16;
    for (int r = wave; r < 16; r += 4) {
        const int i = base + r;
        if (i >= N) break;
        const float4* hv = reinterpret_cast<const float4*>(h + (size_t)i * 256);
        float acc = 0.f;
        #pragma unroll 4
        for (int d4 = 0; d4 < 64; ++d4) {
            float4 a = hv[d4];                 // wave-uniform broadcast load
            const int d = d4 * 4;
            acc = fmaf(a.x, W1s[(d + 0) * 64 + k], acc);
            acc = fmaf(a.y, W1s[(d + 1) * 64 + k], acc);
            acc = fmaf(a.z, W1s[(d + 2) * 64 + k], acc);
            acc = fmaf(a.w, W1s[(d + 3) * 64 + k], acc);
        }
        float v = fmaxf(acc + b1k, 0.f) * w2k;
        #pragma unroll
        for (int off = 32; off > 0; off >>= 1) v += __shfl_down(v, off);
        if (k == 0) e_out[i] = 1.f / (1.f + expf(-(v + b2v)));
    }
}

// ---------------- Kernel 2: h_out[i,:] = sum_{j: A[i,j]>0} e[j] * h[j,:] -------
// One wave per row; lane d owns features 4d..4d+3 (float4 acc).
// A is scanned with NON-TEMPORAL float4 loads (zero reuse -> don't thrash L2).
// Column-panel loop (2048 cols = 2 MB of h) keeps the active h-panel hot in
// each XCD's L2: all 8192 waves are exactly co-resident, so they sweep panels
// near-lockstep. Nonzero iteration is 2-wide unrolled for memory-level ||ism.
__global__ __launch_bounds__(256) void agg_kernel(const float* __restrict__ A,
                                                  const float* __restrict__ h,
                                                  const float* __restrict__ e,
                                                  float* __restrict__ h_out,
                                                  int N) {
    const int tid  = threadIdx.x;
    const int lane = tid & 63;
    const int i    = blockIdx.x * 4 + (tid >> 6);   // row per wave
    if (i >= N) return;

    const nfloat4* Arow = reinterpret_cast<const nfloat4*>(A + (size_t)i * N);
    const float4*  hv   = reinterpret_cast<const float4*>(h);  // h[j][4d..] = hv[j*64+d]

    float4 acc = {0.f, 0.f, 0.f, 0.f};

    // processes one ballot mask; columns j = jb + 4*bit + sub
    auto process_mask = [&](unsigned long long m, int jb, int sub) {
        while (m) {
            int b0 = __builtin_ctzll(m); m &= m - 1;
            int j0 = jb + 4 * b0 + sub;
            if (m) {
                int b1 = __builtin_ctzll(m); m &= m - 1;
                int j1 = jb + 4 * b1 + sub;
                float  e0 = e[j0], e1 = e[j1];
                float4 h0 = hv[(size_t)j0 * 64 + lane];
                float4 h1 = hv[(size_t)j1 * 64 + lane];
                acc.x = fmaf(e0, h0.x, acc.x); acc.y = fmaf(e0, h0.y, acc.y);
                acc.z = fmaf(e0, h0.z, acc.z); acc.w = fmaf(e0, h0.w, acc.w);
                acc.x = fmaf(e1, h1.x, acc.x); acc.y = fmaf(e1, h1.y, acc.y);
                acc.z = fmaf(e1, h1.z, acc.z); acc.w = fmaf(e1, h1.w, acc.w);
            } else {
                float  e0 = e[j0];
                float4 h0 = hv[(size_t)j0 * 64 + lane];
                acc.x = fmaf(e0, h0.x, acc.x); acc.y = fmaf(e0, h0.y, acc.y);
                acc.z = fmaf(e0, h0.z, acc.z); acc.w = fmaf(e0, h0.w, acc.w);
            }
        }
    };

    constexpr int PANEL = 2048;                     // 2 MB h-panel in L2
    for (int p0 = 0; p0 < N; p0 += PANEL) {
        const int gBeg = p0 >> 8;                   // 256 cols per group
        const int gEnd = (p0 + PANEL) >> 8;
        for (int g = gBeg; g < gEnd; ++g) {
            nfloat4 a4 = __builtin_nontemporal_load(&Arow[g * 64 + lane]);
            unsigned long long mx = __ballot(a4.x > 0.f);
            unsigned long long my = __ballot(a4.y > 0.f);
            unsigned long long mz = __ballot(a4.z > 0.f);
            unsigned long long mw = __ballot(a4.w > 0.f);
            const int jb = g * 256;
            process_mask(mx, jb, 0);
            process_mask(my, jb, 1);
            process_mask(mz, jb, 2);
            process_mask(mw, jb, 3);
        }
    }

    float4* outv = reinterpret_cast<float4*>(h_out + (size_t)i * 256);
    outv[lane] = acc;
}

extern "C" void kernel_launch(void* const* d_in, const int* in_sizes, int n_in,
                              void* d_out, int out_size, void* d_ws, size_t ws_size,
                              hipStream_t stream) {
    const float* A  = (const float*)d_in[0];   // [N, N]
    const float* h  = (const float*)d_in[1];   // [N, D]
    const float* W1 = (const float*)d_in[2];   // [D, H]
    const float* b1 = (const float*)d_in[3];   // [H]
    const float* W2 = (const float*)d_in[4];   // [H, 1]
    const float* b2 = (const float*)d_in[5];   // [1]

    const int H = in_sizes[3];                 // 64
    const int D = in_sizes[2] / H;             // 256
    const int N = in_sizes[1] / D;             // 8192

    float* out   = (float*)d_out;
    float* h_out = out;                        // N*D
    float* e_out = out + (size_t)N * D;        // N

    gate_kernel<<<(N + 15) / 16, 256, 0, stream>>>(h, W1, b1, W2, b2, e_out, N);
    agg_kernel<<<(N + 3) / 4, 256, 0, stream>>>(A, h, e_out, h_out, N);
}